// Round 3
// baseline (964.546 us; speedup 1.0000x reference)
//
#include <hip/hip_runtime.h>
#include <hip/hip_bf16.h>
#include <hip/hip_cooperative_groups.h>

namespace cg = cooperative_groups;

#define NB 2
#define NC 16
#define NN 8192
#define NBC 32            // NB*NC columns of the skinny GEMM
#define KS 8              // fallback k-split
#define CWAVES 8          // waves per block in cooperative kernel
#define CROWS 16          // output rows per block
#define CBLKS (NN / CROWS)  // 512 blocks
#define STEP_ELEMS (NB * NN * NC)

typedef float f32x4 __attribute__((ext_vector_type(4)));
typedef __bf16 bf16x8 __attribute__((ext_vector_type(8)));

// ---------------- GroupNorm stats: one block per (b,g), 16 blocks ----------------
__global__ void gn_stats_k(const float* __restrict__ c, float* __restrict__ stats) {
    int bg = blockIdx.x;                       // b*8 + g
    const float* p = c + (size_t)bg * 16384;
    float s = 0.f, ss = 0.f;
    for (int i = threadIdx.x; i < 4096; i += 256) {
        float4 v = ((const float4*)p)[i];
        s  += v.x + v.y + v.z + v.w;
        ss += v.x*v.x + v.y*v.y + v.z*v.z + v.w*v.w;
    }
    #pragma unroll
    for (int o = 32; o; o >>= 1) { s += __shfl_down(s, o); ss += __shfl_down(ss, o); }
    __shared__ float sh[8];
    int w = threadIdx.x >> 6;
    if ((threadIdx.x & 63) == 0) { sh[w] = s; sh[w + 4] = ss; }
    __syncthreads();
    if (threadIdx.x == 0) {
        float S = sh[0]+sh[1]+sh[2]+sh[3], SS = sh[4]+sh[5]+sh[6]+sh[7];
        float mu = S * (1.f/16384.f);
        float var = SS * (1.f/16384.f) - mu*mu;
        stats[bg*2]   = mu;
        stats[bg*2+1] = rsqrtf(var + 1e-5f);
    }
}

// ---------------- y = GN(c)^T, x0 = normalize(x^T); write f32 state + bf16 X ----------------
__global__ void prep_xy_k(const float* __restrict__ x, const float* __restrict__ c,
                          const float* __restrict__ gnw, const float* __restrict__ gnb,
                          const float* __restrict__ stats,
                          float* __restrict__ y_arr, float* __restrict__ x0f,
                          __bf16* __restrict__ Xbf) {
    int tid = blockIdx.x * 256 + threadIdx.x;  // 131072 = B*N*8
    int n = tid & (NN - 1);
    int j = (tid >> 13) & 7;
    int b = tid >> 16;
    int ch0 = 2 * j;
    size_t r0 = ((size_t)(b * NC + ch0)) * NN + n;
    float c0 = c[r0], c1 = c[r0 + NN];
    float x0 = x[r0], x1 = x[r0 + NN];
    float mu = stats[(b*8 + j)*2], rstd = stats[(b*8 + j)*2 + 1];
    float y0 = (c0 - mu) * rstd * gnw[ch0]   + gnb[ch0];
    float y1 = (c1 - mu) * rstd * gnw[ch0+1] + gnb[ch0+1];
    int base = n * NBC + b * NC + ch0;
    y_arr[base] = y0; y_arr[base + 1] = y1;
    float inv = 1.f / (sqrtf(x0*x0 + x1*x1) + 1e-6f);
    x0 *= inv; x1 *= inv;
    size_t xi = ((size_t)(b * NN + n)) * NC + ch0;
    x0f[xi] = x0; x0f[xi + 1] = x1;
    Xbf[(size_t)(b*NC + ch0)     * NN + n] = (__bf16)x0;
    Xbf[(size_t)(b*NC + ch0 + 1) * NN + n] = (__bf16)x1;
}

// ---------------- A = bf16(sc * conn_w); nontemporal reads keep L3 for A ----------------
__global__ void prep_A_k(const float* __restrict__ sc, const float* __restrict__ cw,
                         __bf16* __restrict__ Abf) {
    size_t i = ((size_t)blockIdx.x * 256 + threadIdx.x) * 16;
    const f32x4* sp = (const f32x4*)(sc + i);
    const f32x4* wp = (const f32x4*)(cw + i);
    f32x4 s0 = __builtin_nontemporal_load(sp);
    f32x4 s1 = __builtin_nontemporal_load(sp + 1);
    f32x4 s2 = __builtin_nontemporal_load(sp + 2);
    f32x4 s3 = __builtin_nontemporal_load(sp + 3);
    f32x4 w0 = __builtin_nontemporal_load(wp);
    f32x4 w1 = __builtin_nontemporal_load(wp + 1);
    f32x4 w2 = __builtin_nontemporal_load(wp + 2);
    f32x4 w3 = __builtin_nontemporal_load(wp + 3);
    bf16x8 o0, o1;
    o0[0]=(__bf16)(s0[0]*w0[0]); o0[1]=(__bf16)(s0[1]*w0[1]);
    o0[2]=(__bf16)(s0[2]*w0[2]); o0[3]=(__bf16)(s0[3]*w0[3]);
    o0[4]=(__bf16)(s1[0]*w1[0]); o0[5]=(__bf16)(s1[1]*w1[1]);
    o0[6]=(__bf16)(s1[2]*w1[2]); o0[7]=(__bf16)(s1[3]*w1[3]);
    o1[0]=(__bf16)(s2[0]*w2[0]); o1[1]=(__bf16)(s2[1]*w2[1]);
    o1[2]=(__bf16)(s2[2]*w2[2]); o1[3]=(__bf16)(s2[3]*w2[3]);
    o1[4]=(__bf16)(s3[0]*w3[0]); o1[5]=(__bf16)(s3[1]*w3[1]);
    o1[6]=(__bf16)(s3[2]*w3[2]); o1[7]=(__bf16)(s3[3]*w3[3]);
    *(bf16x8*)(Abf + i)     = o0;
    *(bf16x8*)(Abf + i + 8) = o1;
}

// ---------------- cooperative Q-loop: all 8 steps in one kernel ----------------
// 512 blocks x 512 threads (2 blocks/CU co-resident). Block mb owns rows
// [mb*16, mb*16+16). 8 waves split K 8-ways, LDS-reduce, threads 0..255 do the
// oscillator update with x-state in registers; one grid.sync per step.
__global__ __launch_bounds__(512, 4) void km_loop_k(
    const __bf16* __restrict__ Abf, const float* __restrict__ y_arr,
    const float* __restrict__ x0f, const float* __restrict__ omg,
    const float* __restrict__ gamma, __bf16* __restrict__ Xa,
    __bf16* __restrict__ Xb, float* __restrict__ out, int Q)
{
    cg::grid_group grid = cg::this_grid();
    __shared__ float red[CWAVES][CROWS][NBC + 1];
    int tid = threadIdx.x;
    int lane = tid & 63, w = tid >> 6;
    int mb = blockIdx.x;

    // persistent per-thread oscillator state (threads 0..255)
    float xs0 = 0.f, xs1 = 0.f, y0 = 0.f, y1 = 0.f, om = 0.f, g = 0.f;
    size_t xi = 0; int r_ = 0, cb = 0, n_ = 0;
    bool upd = (tid < CROWS * 16);
    if (upd) {
        int pi = tid & 15, b = pi >> 3, j = pi & 7;
        r_ = tid >> 4;
        n_ = mb * CROWS + r_;
        cb = b * NC + 2 * j;
        int yb = n_ * NBC + cb;
        y0 = y_arr[yb]; y1 = y_arr[yb + 1];
        xi = ((size_t)(b * NN + n_)) * NC + 2 * j;
        xs0 = x0f[xi]; xs1 = x0f[xi + 1];
        om = fabsf(omg[j]); g = gamma[0];
    }

    const int KW = NN / CWAVES;   // 1024 per wave
    const __bf16* ap = Abf + (size_t)(mb * CROWS + (lane & 15)) * NN + w * KW + ((lane >> 4) * 8);
    size_t bo = (size_t)(lane & 15) * NN + w * KW + ((lane >> 4) * 8);

    __bf16* Xc = Xa; __bf16* Xn = Xb;
    for (int q = 0; q < Q; ++q) {
        const __bf16* bp0 = Xc + bo;
        const __bf16* bp1 = bp0 + (size_t)16 * NN;
        f32x4 acc0 = {0.f,0.f,0.f,0.f}, acc1 = {0.f,0.f,0.f,0.f};
        // depth-4 software pipeline: 12 loads in flight
        bf16x8 A[4], B0[4], B1[4];
        #pragma unroll
        for (int s = 0; s < 4; ++s) {
            A[s]  = *(const bf16x8*)(ap  + s * 32);
            B0[s] = *(const bf16x8*)(bp0 + s * 32);
            B1[s] = *(const bf16x8*)(bp1 + s * 32);
        }
        #pragma unroll
        for (int k = 0; k < KW; k += 128) {
            #pragma unroll
            for (int s = 0; s < 4; ++s) {
                bf16x8 a = A[s], b0 = B0[s], b1 = B1[s];
                int kp = k + s * 32 + 128;
                if (kp < KW) {
                    A[s]  = *(const bf16x8*)(ap  + kp);
                    B0[s] = *(const bf16x8*)(bp0 + kp);
                    B1[s] = *(const bf16x8*)(bp1 + kp);
                }
                acc0 = __builtin_amdgcn_mfma_f32_16x16x32_bf16(a, b0, acc0, 0, 0, 0);
                acc1 = __builtin_amdgcn_mfma_f32_16x16x32_bf16(a, b1, acc1, 0, 0, 0);
            }
        }
        // C/D layout: col = lane&15, row = (lane>>4)*4 + r  [HW-verified]
        int orow = (lane >> 4) * 4, ocol = lane & 15;
        #pragma unroll
        for (int r4 = 0; r4 < 4; ++r4) {
            red[w][orow + r4][ocol]      = acc0[r4];
            red[w][orow + r4][ocol + 16] = acc1[r4];
        }
        __syncthreads();
        if (upd) {
            float c0 = 0.f, c1 = 0.f;
            #pragma unroll
            for (int ww = 0; ww < CWAVES; ++ww) {
                c0 += red[ww][r_][cb];
                c1 += red[ww][r_][cb + 1];
            }
            float yy0 = y0 + c0, yy1 = y1 + c1;
            float sim = xs0 * yy0 + xs1 * yy1;
            float p0 = yy0 - sim * xs0;
            float p1 = yy1 - sim * xs1;
            float v0 = xs0 + g * ( om * xs1 + p0);
            float v1 = xs1 + g * (-om * xs0 + p1);
            float inv = 1.f / (sqrtf(v0*v0 + v1*v1) + 1e-6f);
            xs0 = v0 * inv; xs1 = v1 * inv;
            out[(size_t)q * STEP_ELEMS + xi]     = xs0;
            out[(size_t)q * STEP_ELEMS + xi + 1] = xs1;
            Xn[(size_t)cb * NN + n_]       = (__bf16)xs0;
            Xn[(size_t)(cb + 1) * NN + n_] = (__bf16)xs1;
        }
        grid.sync();
        __bf16* t = Xc; Xc = Xn; Xn = t;
    }
}

// ---------------- fallback path (non-cooperative) ----------------
__device__ inline bf16x8 mulcvt8(const float* __restrict__ s, const float* __restrict__ w) {
    f32x4 s0 = ((const f32x4*)s)[0], s1 = ((const f32x4*)s)[1];
    f32x4 w0 = ((const f32x4*)w)[0], w1 = ((const f32x4*)w)[1];
    bf16x8 r;
    r[0]=(__bf16)(s0[0]*w0[0]); r[1]=(__bf16)(s0[1]*w0[1]);
    r[2]=(__bf16)(s0[2]*w0[2]); r[3]=(__bf16)(s0[3]*w0[3]);
    r[4]=(__bf16)(s1[0]*w1[0]); r[5]=(__bf16)(s1[1]*w1[1]);
    r[6]=(__bf16)(s1[2]*w1[2]); r[7]=(__bf16)(s1[3]*w1[3]);
    return r;
}

template<bool FUSED>
__global__ __launch_bounds__(256) void gemm_step_k(const __bf16* __restrict__ Abf,
                                                   const float* __restrict__ sc,
                                                   const float* __restrict__ cw,
                                                   const __bf16* __restrict__ Xbf,
                                                   float* __restrict__ part) {
    int mb = blockIdx.x;
    int ks = blockIdx.y;
    int lane = threadIdx.x & 63;
    int w = threadIdx.x >> 6;
    int row = mb * 64 + w * 16 + (lane & 15);
    int kb  = (lane >> 4) * 8;
    int k0  = ks * (NN / KS);
    f32x4 acc0 = {0.f,0.f,0.f,0.f}, acc1 = {0.f,0.f,0.f,0.f};
    const __bf16* bp0 = Xbf + (size_t)(lane & 15) * NN + k0 + kb;
    const __bf16* bp1 = bp0 + (size_t)16 * NN;
    if (FUSED) {
        const float* as = sc + (size_t)row * NN + k0 + kb;
        const float* aw = cw + (size_t)row * NN + k0 + kb;
        #pragma unroll 4
        for (int k = 0; k < NN / KS; k += 32) {
            bf16x8 a  = mulcvt8(as + k, aw + k);
            bf16x8 b0 = *(const bf16x8*)(bp0 + k);
            bf16x8 b1 = *(const bf16x8*)(bp1 + k);
            acc0 = __builtin_amdgcn_mfma_f32_16x16x32_bf16(a, b0, acc0, 0, 0, 0);
            acc1 = __builtin_amdgcn_mfma_f32_16x16x32_bf16(a, b1, acc1, 0, 0, 0);
        }
    } else {
        const __bf16* ap = Abf + (size_t)row * NN + k0 + kb;
        #pragma unroll 8
        for (int k = 0; k < NN / KS; k += 32) {
            bf16x8 a  = *(const bf16x8*)(ap + k);
            bf16x8 b0 = *(const bf16x8*)(bp0 + k);
            bf16x8 b1 = *(const bf16x8*)(bp1 + k);
            acc0 = __builtin_amdgcn_mfma_f32_16x16x32_bf16(a, b0, acc0, 0, 0, 0);
            acc1 = __builtin_amdgcn_mfma_f32_16x16x32_bf16(a, b1, acc1, 0, 0, 0);
        }
    }
    int orow = mb * 64 + w * 16 + (lane >> 4) * 4;
    int ocol = lane & 15;
    float* pp = part + (size_t)ks * NN * NBC + (size_t)orow * NBC + ocol;
    #pragma unroll
    for (int r = 0; r < 4; ++r) {
        pp[(size_t)r * NBC]      = acc0[r];
        pp[(size_t)r * NBC + 16] = acc1[r];
    }
}

__global__ void update_step_k(const float* __restrict__ part, const float* __restrict__ y_arr,
                              const float* __restrict__ omg, const float* __restrict__ gamma,
                              float* __restrict__ x0f, __bf16* __restrict__ Xbf,
                              float* __restrict__ out_k) {
    int tid = blockIdx.x * 256 + threadIdx.x;   // 131072
    int j = tid & 7;
    int n = (tid >> 3) & (NN - 1);
    int b = tid >> 16;
    int base = n * NBC + b * NC + 2 * j;
    float c0 = 0.f, c1 = 0.f;
    #pragma unroll
    for (int ks = 0; ks < KS; ++ks) {
        const float* p = part + (size_t)ks * NN * NBC + base;
        c0 += p[0]; c1 += p[1];
    }
    float y0 = y_arr[base] + c0;
    float y1 = y_arr[base + 1] + c1;
    size_t xi = ((size_t)(b * NN + n)) * NC + 2 * j;
    float x0 = x0f[xi], x1 = x0f[xi + 1];
    float sim = x0 * y0 + x1 * y1;
    float p0 = y0 - sim * x0;
    float p1 = y1 - sim * x1;
    float om = fabsf(omg[j]);
    float g  = gamma[0];
    float v0 = x0 + g * ( om * x1 + p0);
    float v1 = x1 + g * (-om * x0 + p1);
    float inv = 1.f / (sqrtf(v0*v0 + v1*v1) + 1e-6f);
    v0 *= inv; v1 *= inv;
    out_k[xi] = v0; out_k[xi + 1] = v1;
    x0f[xi] = v0; x0f[xi + 1] = v1;
    Xbf[(size_t)(b*NC + 2*j)     * NN + n] = (__bf16)v0;
    Xbf[(size_t)(b*NC + 2*j + 1) * NN + n] = (__bf16)v1;
}

extern "C" void kernel_launch(void* const* d_in, const int* in_sizes, int n_in,
                              void* d_out, int out_size, void* d_ws, size_t ws_size,
                              hipStream_t stream) {
    const float* x     = (const float*)d_in[0];
    const float* c     = (const float*)d_in[1];
    const float* sc    = (const float*)d_in[2];
    const float* gnw   = (const float*)d_in[3];
    const float* gnb   = (const float*)d_in[4];
    const float* cw    = (const float*)d_in[5];
    const float* omg   = (const float*)d_in[6];
    const float* gamma = (const float*)d_in[7];
    float* out = (float*)d_out;
    int Q = out_size / STEP_ELEMS;

    const size_t szA   = (size_t)NN * NN * 2;        // 128 MiB
    const size_t szX   = (size_t)NBC * NN * 2;       // 512 KiB each
    const size_t szX0f = (size_t)NB * NN * NC * 4;   // 1 MiB
    const size_t szY   = (size_t)NN * NBC * 4;       // 1 MiB
    const size_t szPart = (size_t)KS * NN * NBC * 4; // 8 MiB (fallback only)
    const size_t rest = 2*szX + szX0f + szY + szPart + 256;
    bool bigws = ws_size >= szA + rest;

    char* p = (char*)d_ws;
    __bf16* Abf = nullptr;
    if (bigws) { Abf = (__bf16*)p; p += szA; }
    __bf16* Xa   = (__bf16*)p; p += szX;
    __bf16* Xb   = (__bf16*)p; p += szX;
    float* x0f   = (float*)p;  p += szX0f;
    float* y_arr = (float*)p;  p += szY;
    float* part  = (float*)p;  p += szPart;
    float* stats = (float*)p;  p += 256;

    gn_stats_k<<<16, 256, 0, stream>>>(c, stats);
    prep_xy_k<<<(NB * NN * 8) / 256, 256, 0, stream>>>(x, c, gnw, gnb, stats, y_arr, x0f, Xa);

    if (bigws) {
        prep_A_k<<<((size_t)NN * NN / 16) / 256, 256, 0, stream>>>(sc, cw, Abf);
        void* args[] = { (void*)&Abf, (void*)&y_arr, (void*)&x0f, (void*)&omg,
                         (void*)&gamma, (void*)&Xa, (void*)&Xb, (void*)&out, (void*)&Q };
        hipError_t e = hipLaunchCooperativeKernel(km_loop_k, dim3(CBLKS), dim3(CWAVES * 64),
                                                  args, 0, stream);
        if (e == hipSuccess) return;
        // cooperative launch unavailable -> fall back to multi-kernel path
        dim3 gg(NN / 64, KS);
        for (int k = 0; k < Q; ++k) {
            gemm_step_k<false><<<gg, 256, 0, stream>>>(Abf, sc, cw, Xa, part);
            update_step_k<<<(NB * NN * 8) / 256, 256, 0, stream>>>(
                part, y_arr, omg, gamma, x0f, Xa, out + (size_t)k * STEP_ELEMS);
        }
        return;
    }

    dim3 gg(NN / 64, KS);
    for (int k = 0; k < Q; ++k) {
        gemm_step_k<true><<<gg, 256, 0, stream>>>(nullptr, sc, cw, Xa, part);
        update_step_k<<<(NB * NN * 8) / 256, 256, 0, stream>>>(
            part, y_arr, omg, gamma, x0f, Xa, out + (size_t)k * STEP_ELEMS);
    }
}

// Round 4
// 589.981 us; speedup vs baseline: 1.6349x; 1.6349x over previous
//
#include <hip/hip_runtime.h>
#include <hip/hip_bf16.h>

#define NB 2
#define NC 16
#define NN 8192
#define NBC 32   // NB*NC columns of the skinny GEMM
#define KS 16    // K-split factor
#define STEP_ELEMS (NB * NN * NC)

typedef float f32x4 __attribute__((ext_vector_type(4)));
typedef __bf16 bf16x8 __attribute__((ext_vector_type(8)));

// ---------------- GroupNorm stats: one block per (b,g), 16 blocks ----------------
__global__ void gn_stats_k(const float* __restrict__ c, float* __restrict__ stats) {
    int bg = blockIdx.x;                       // b*8 + g
    const float* p = c + (size_t)bg * 16384;
    float s = 0.f, ss = 0.f;
    for (int i = threadIdx.x; i < 4096; i += 256) {
        float4 v = ((const float4*)p)[i];
        s  += v.x + v.y + v.z + v.w;
        ss += v.x*v.x + v.y*v.y + v.z*v.z + v.w*v.w;
    }
    #pragma unroll
    for (int o = 32; o; o >>= 1) { s += __shfl_down(s, o); ss += __shfl_down(ss, o); }
    __shared__ float sh[8];
    int w = threadIdx.x >> 6;
    if ((threadIdx.x & 63) == 0) { sh[w] = s; sh[w + 4] = ss; }
    __syncthreads();
    if (threadIdx.x == 0) {
        float S = sh[0]+sh[1]+sh[2]+sh[3], SS = sh[4]+sh[5]+sh[6]+sh[7];
        float mu = S * (1.f/16384.f);
        float var = SS * (1.f/16384.f) - mu*mu;
        stats[bg*2]   = mu;
        stats[bg*2+1] = rsqrtf(var + 1e-5f);
    }
}

// ---------------- y = GN(c)^T, x0 = normalize(x^T); write f32 state + bf16 X ----------------
__global__ void prep_xy_k(const float* __restrict__ x, const float* __restrict__ c,
                          const float* __restrict__ gnw, const float* __restrict__ gnb,
                          const float* __restrict__ stats,
                          float* __restrict__ y_arr, float* __restrict__ x0f,
                          __bf16* __restrict__ Xbf) {
    int tid = blockIdx.x * 256 + threadIdx.x;  // 131072 = B*N*8
    int n = tid & (NN - 1);
    int j = (tid >> 13) & 7;
    int b = tid >> 16;
    int ch0 = 2 * j;
    size_t r0 = ((size_t)(b * NC + ch0)) * NN + n;
    float c0 = c[r0], c1 = c[r0 + NN];
    float x0 = x[r0], x1 = x[r0 + NN];
    float mu = stats[(b*8 + j)*2], rstd = stats[(b*8 + j)*2 + 1];
    float y0 = (c0 - mu) * rstd * gnw[ch0]   + gnb[ch0];
    float y1 = (c1 - mu) * rstd * gnw[ch0+1] + gnb[ch0+1];
    int base = n * NBC + b * NC + ch0;
    y_arr[base] = y0; y_arr[base + 1] = y1;
    float inv = 1.f / (sqrtf(x0*x0 + x1*x1) + 1e-6f);
    x0 *= inv; x1 *= inv;
    size_t xi = ((size_t)(b * NN + n)) * NC + ch0;
    x0f[xi] = x0; x0f[xi + 1] = x1;
    Xbf[(size_t)(b*NC + ch0)     * NN + n] = (__bf16)x0;
    Xbf[(size_t)(b*NC + ch0 + 1) * NN + n] = (__bf16)x1;
}

// ---------------- A = bf16(sc * conn_w); nontemporal reads keep L3 for A ----------------
__global__ void prep_A_k(const float* __restrict__ sc, const float* __restrict__ cw,
                         __bf16* __restrict__ Abf) {
    size_t i = ((size_t)blockIdx.x * 256 + threadIdx.x) * 16;
    const f32x4* sp = (const f32x4*)(sc + i);
    const f32x4* wp = (const f32x4*)(cw + i);
    f32x4 s0 = __builtin_nontemporal_load(sp);
    f32x4 s1 = __builtin_nontemporal_load(sp + 1);
    f32x4 s2 = __builtin_nontemporal_load(sp + 2);
    f32x4 s3 = __builtin_nontemporal_load(sp + 3);
    f32x4 w0 = __builtin_nontemporal_load(wp);
    f32x4 w1 = __builtin_nontemporal_load(wp + 1);
    f32x4 w2 = __builtin_nontemporal_load(wp + 2);
    f32x4 w3 = __builtin_nontemporal_load(wp + 3);
    bf16x8 o0, o1;
    o0[0]=(__bf16)(s0[0]*w0[0]); o0[1]=(__bf16)(s0[1]*w0[1]);
    o0[2]=(__bf16)(s0[2]*w0[2]); o0[3]=(__bf16)(s0[3]*w0[3]);
    o0[4]=(__bf16)(s1[0]*w1[0]); o0[5]=(__bf16)(s1[1]*w1[1]);
    o0[6]=(__bf16)(s1[2]*w1[2]); o0[7]=(__bf16)(s1[3]*w1[3]);
    o1[0]=(__bf16)(s2[0]*w2[0]); o1[1]=(__bf16)(s2[1]*w2[1]);
    o1[2]=(__bf16)(s2[2]*w2[2]); o1[3]=(__bf16)(s2[3]*w2[3]);
    o1[4]=(__bf16)(s3[0]*w3[0]); o1[5]=(__bf16)(s3[1]*w3[1]);
    o1[6]=(__bf16)(s3[2]*w3[2]); o1[7]=(__bf16)(s3[3]*w3[3]);
    *(bf16x8*)(Abf + i)     = o0;
    *(bf16x8*)(Abf + i + 8) = o1;
}

__device__ inline bf16x8 mulcvt8(const float* __restrict__ s, const float* __restrict__ w) {
    f32x4 s0 = ((const f32x4*)s)[0], s1 = ((const f32x4*)s)[1];
    f32x4 w0 = ((const f32x4*)w)[0], w1 = ((const f32x4*)w)[1];
    bf16x8 r;
    r[0]=(__bf16)(s0[0]*w0[0]); r[1]=(__bf16)(s0[1]*w0[1]);
    r[2]=(__bf16)(s0[2]*w0[2]); r[3]=(__bf16)(s0[3]*w0[3]);
    r[4]=(__bf16)(s1[0]*w1[0]); r[5]=(__bf16)(s1[1]*w1[1]);
    r[6]=(__bf16)(s1[2]*w1[2]); r[7]=(__bf16)(s1[3]*w1[3]);
    return r;
}

// ---------------- coup partials = A(chunk) @ X : grid (128 m-blocks, KS=16) ----------------
// 2048 blocks x 4 waves -> ~32 waves/CU. Explicit depth-2 pipeline over 64-wide
// K steps: 6 independent 16B loads issued ahead of 4 MFMAs.
template<bool FUSED>
__global__ __launch_bounds__(256) void gemm_step_k(const __bf16* __restrict__ Abf,
                                                   const float* __restrict__ sc,
                                                   const float* __restrict__ cw,
                                                   const __bf16* __restrict__ Xbf,
                                                   float* __restrict__ part) {
    int mb = blockIdx.x;
    int ks = blockIdx.y;
    int lane = threadIdx.x & 63;
    int w = threadIdx.x >> 6;
    int row = mb * 64 + w * 16 + (lane & 15);
    int kb  = (lane >> 4) * 8;
    int k0  = ks * (NN / KS);
    const int KC = NN / KS;  // 512
    f32x4 acc0 = {0.f,0.f,0.f,0.f}, acc1 = {0.f,0.f,0.f,0.f};
    const __bf16* bp0 = Xbf + (size_t)(lane & 15) * NN + k0 + kb;
    const __bf16* bp1 = bp0 + (size_t)16 * NN;
    if (FUSED) {
        const float* as = sc + (size_t)row * NN + k0 + kb;
        const float* aw = cw + (size_t)row * NN + k0 + kb;
        #pragma unroll 4
        for (int k = 0; k < KC; k += 32) {
            bf16x8 a  = mulcvt8(as + k, aw + k);
            bf16x8 b0 = *(const bf16x8*)(bp0 + k);
            bf16x8 b1 = *(const bf16x8*)(bp1 + k);
            acc0 = __builtin_amdgcn_mfma_f32_16x16x32_bf16(a, b0, acc0, 0, 0, 0);
            acc1 = __builtin_amdgcn_mfma_f32_16x16x32_bf16(a, b1, acc1, 0, 0, 0);
        }
    } else {
        const __bf16* ap = Abf + (size_t)row * NN + k0 + kb;
        bf16x8 a0  = *(const bf16x8*)(ap);
        bf16x8 a1  = *(const bf16x8*)(ap + 32);
        bf16x8 b00 = *(const bf16x8*)(bp0);
        bf16x8 b01 = *(const bf16x8*)(bp0 + 32);
        bf16x8 b10 = *(const bf16x8*)(bp1);
        bf16x8 b11 = *(const bf16x8*)(bp1 + 32);
        #pragma unroll
        for (int k = 0; k < KC - 64; k += 64) {
            bf16x8 na0  = *(const bf16x8*)(ap  + k + 64);
            bf16x8 na1  = *(const bf16x8*)(ap  + k + 96);
            bf16x8 nb00 = *(const bf16x8*)(bp0 + k + 64);
            bf16x8 nb01 = *(const bf16x8*)(bp0 + k + 96);
            bf16x8 nb10 = *(const bf16x8*)(bp1 + k + 64);
            bf16x8 nb11 = *(const bf16x8*)(bp1 + k + 96);
            acc0 = __builtin_amdgcn_mfma_f32_16x16x32_bf16(a0, b00, acc0, 0, 0, 0);
            acc1 = __builtin_amdgcn_mfma_f32_16x16x32_bf16(a0, b10, acc1, 0, 0, 0);
            acc0 = __builtin_amdgcn_mfma_f32_16x16x32_bf16(a1, b01, acc0, 0, 0, 0);
            acc1 = __builtin_amdgcn_mfma_f32_16x16x32_bf16(a1, b11, acc1, 0, 0, 0);
            a0 = na0; a1 = na1; b00 = nb00; b01 = nb01; b10 = nb10; b11 = nb11;
        }
        acc0 = __builtin_amdgcn_mfma_f32_16x16x32_bf16(a0, b00, acc0, 0, 0, 0);
        acc1 = __builtin_amdgcn_mfma_f32_16x16x32_bf16(a0, b10, acc1, 0, 0, 0);
        acc0 = __builtin_amdgcn_mfma_f32_16x16x32_bf16(a1, b01, acc0, 0, 0, 0);
        acc1 = __builtin_amdgcn_mfma_f32_16x16x32_bf16(a1, b11, acc1, 0, 0, 0);
    }
    // C/D layout: col = lane&15, row = (lane>>4)*4 + r  [HW-verified]
    int orow = mb * 64 + w * 16 + (lane >> 4) * 4;
    int ocol = lane & 15;
    float* pp = part + (size_t)ks * NN * NBC + (size_t)orow * NBC + ocol;
    #pragma unroll
    for (int r = 0; r < 4; ++r) {
        pp[(size_t)r * NBC]      = acc0[r];
        pp[(size_t)r * NBC + 16] = acc1[r];
    }
}

// ---------------- oscillator update: channel bits in low lane bits for coalesced part read ----------------
__global__ void update_step_k(const float* __restrict__ part, const float* __restrict__ y_arr,
                              const float* __restrict__ omg, const float* __restrict__ gamma,
                              float* __restrict__ x0f, __bf16* __restrict__ Xbf,
                              float* __restrict__ out_k) {
    int tid = blockIdx.x * 256 + threadIdx.x;   // 131072
    int pi = tid & 15;          // (b, j)
    int b = pi >> 3, j = pi & 7;
    int n = tid >> 4;           // 0..8191
    int base = n * NBC + b * NC + 2 * j;
    float c0 = 0.f, c1 = 0.f;
    #pragma unroll
    for (int ks = 0; ks < KS; ++ks) {
        const float* p = part + (size_t)ks * NN * NBC + base;
        c0 += p[0]; c1 += p[1];
    }
    float y0 = y_arr[base] + c0;
    float y1 = y_arr[base + 1] + c1;
    size_t xi = ((size_t)(b * NN + n)) * NC + 2 * j;
    float x0 = x0f[xi], x1 = x0f[xi + 1];
    float sim = x0 * y0 + x1 * y1;
    float p0 = y0 - sim * x0;
    float p1 = y1 - sim * x1;
    float om = fabsf(omg[j]);
    float g  = gamma[0];
    float v0 = x0 + g * ( om * x1 + p0);
    float v1 = x1 + g * (-om * x0 + p1);
    float inv = 1.f / (sqrtf(v0*v0 + v1*v1) + 1e-6f);
    v0 *= inv; v1 *= inv;
    out_k[xi] = v0; out_k[xi + 1] = v1;
    x0f[xi] = v0; x0f[xi + 1] = v1;
    Xbf[(size_t)(b*NC + 2*j)     * NN + n] = (__bf16)v0;
    Xbf[(size_t)(b*NC + 2*j + 1) * NN + n] = (__bf16)v1;
}

extern "C" void kernel_launch(void* const* d_in, const int* in_sizes, int n_in,
                              void* d_out, int out_size, void* d_ws, size_t ws_size,
                              hipStream_t stream) {
    const float* x     = (const float*)d_in[0];
    const float* c     = (const float*)d_in[1];
    const float* sc    = (const float*)d_in[2];
    const float* gnw   = (const float*)d_in[3];
    const float* gnb   = (const float*)d_in[4];
    const float* cw    = (const float*)d_in[5];
    const float* omg   = (const float*)d_in[6];
    const float* gamma = (const float*)d_in[7];
    float* out = (float*)d_out;
    int Q = out_size / STEP_ELEMS;

    const size_t szA   = (size_t)NN * NN * 2;        // 128 MiB
    const size_t szXbf = (size_t)NBC * NN * 2;       // 512 KiB
    const size_t szX0f = (size_t)NB * NN * NC * 4;   // 1 MiB
    const size_t szY   = (size_t)NN * NBC * 4;       // 1 MiB
    const size_t szPart = (size_t)KS * NN * NBC * 4; // 16 MiB
    const size_t rest = szXbf + szX0f + szY + szPart + 256;
    bool bigws = ws_size >= szA + rest;

    char* p = (char*)d_ws;
    __bf16* Abf = nullptr;
    if (bigws) { Abf = (__bf16*)p; p += szA; }
    __bf16* Xbf  = (__bf16*)p; p += szXbf;
    float* x0f   = (float*)p;  p += szX0f;
    float* y_arr = (float*)p;  p += szY;
    float* part  = (float*)p;  p += szPart;
    float* stats = (float*)p;  p += 256;

    gn_stats_k<<<16, 256, 0, stream>>>(c, stats);
    prep_xy_k<<<(NB * NN * 8) / 256, 256, 0, stream>>>(x, c, gnw, gnb, stats, y_arr, x0f, Xbf);
    if (bigws)
        prep_A_k<<<((size_t)NN * NN / 16) / 256, 256, 0, stream>>>(sc, cw, Abf);

    dim3 gg(NN / 64, KS);
    for (int k = 0; k < Q; ++k) {
        if (bigws)
            gemm_step_k<false><<<gg, 256, 0, stream>>>(Abf, sc, cw, Xbf, part);
        else
            gemm_step_k<true><<<gg, 256, 0, stream>>>(nullptr, sc, cw, Xbf, part);
        update_step_k<<<(NB * NN * 8) / 256, 256, 0, stream>>>(
            part, y_arr, omg, gamma, x0f, Xbf, out + (size_t)k * STEP_ELEMS);
    }
}

// Round 6
// 564.137 us; speedup vs baseline: 1.7098x; 1.0458x over previous
//
#include <hip/hip_runtime.h>
#include <hip/hip_bf16.h>

#define NB 2
#define NC 16
#define NN 8192
#define NBC 32   // NB*NC columns of the skinny GEMM
#define KS 16    // K-split factor
#define STEP_ELEMS (NB * NN * NC)

typedef float f32x4 __attribute__((ext_vector_type(4)));
typedef __bf16 bf16x8 __attribute__((ext_vector_type(8)));

// ---------------- GroupNorm stats: one block per (b,g), 16 blocks ----------------
__global__ void gn_stats_k(const float* __restrict__ c, float* __restrict__ stats) {
    int bg = blockIdx.x;                       // b*8 + g
    const float* p = c + (size_t)bg * 16384;
    float s = 0.f, ss = 0.f;
    for (int i = threadIdx.x; i < 4096; i += 256) {
        float4 v = ((const float4*)p)[i];
        s  += v.x + v.y + v.z + v.w;
        ss += v.x*v.x + v.y*v.y + v.z*v.z + v.w*v.w;
    }
    #pragma unroll
    for (int o = 32; o; o >>= 1) { s += __shfl_down(s, o); ss += __shfl_down(ss, o); }
    __shared__ float sh[8];
    int w = threadIdx.x >> 6;
    if ((threadIdx.x & 63) == 0) { sh[w] = s; sh[w + 4] = ss; }
    __syncthreads();
    if (threadIdx.x == 0) {
        float S = sh[0]+sh[1]+sh[2]+sh[3], SS = sh[4]+sh[5]+sh[6]+sh[7];
        float mu = S * (1.f/16384.f);
        float var = SS * (1.f/16384.f) - mu*mu;
        stats[bg*2]   = mu;
        stats[bg*2+1] = rsqrtf(var + 1e-5f);
    }
}

// ---------------- y = GN(c)^T, x0 = normalize(x^T); write f32 state + bf16 X ----------------
__global__ void prep_xy_k(const float* __restrict__ x, const float* __restrict__ c,
                          const float* __restrict__ gnw, const float* __restrict__ gnb,
                          const float* __restrict__ stats,
                          float* __restrict__ y_arr, float* __restrict__ x0f,
                          __bf16* __restrict__ Xbf) {
    int tid = blockIdx.x * 256 + threadIdx.x;  // 131072 = B*N*8
    int n = tid & (NN - 1);
    int j = (tid >> 13) & 7;
    int b = tid >> 16;
    int ch0 = 2 * j;
    size_t r0 = ((size_t)(b * NC + ch0)) * NN + n;
    float c0 = c[r0], c1 = c[r0 + NN];
    float x0 = x[r0], x1 = x[r0 + NN];
    float mu = stats[(b*8 + j)*2], rstd = stats[(b*8 + j)*2 + 1];
    float y0 = (c0 - mu) * rstd * gnw[ch0]   + gnb[ch0];
    float y1 = (c1 - mu) * rstd * gnw[ch0+1] + gnb[ch0+1];
    int base = n * NBC + b * NC + ch0;
    y_arr[base] = y0; y_arr[base + 1] = y1;
    float inv = 1.f / (sqrtf(x0*x0 + x1*x1) + 1e-6f);
    x0 *= inv; x1 *= inv;
    size_t xi = ((size_t)(b * NN + n)) * NC + ch0;
    x0f[xi] = x0; x0f[xi + 1] = x1;
    Xbf[(size_t)(b*NC + ch0)     * NN + n] = (__bf16)x0;
    Xbf[(size_t)(b*NC + ch0 + 1) * NN + n] = (__bf16)x1;
}

// ---------------- A = bf16(sc * conn_w); split into 8 dispatches for rocprof visibility ----------------
__global__ __launch_bounds__(256) void prep_A_k(const float* __restrict__ sc,
                                                const float* __restrict__ cw,
                                                __bf16* __restrict__ Abf, size_t base) {
    size_t i = base + ((size_t)blockIdx.x * 256 + threadIdx.x) * 16;
    const f32x4* sp = (const f32x4*)(sc + i);
    const f32x4* wp = (const f32x4*)(cw + i);
    f32x4 s0 = sp[0], s1 = sp[1], s2 = sp[2], s3 = sp[3];
    f32x4 w0 = wp[0], w1 = wp[1], w2 = wp[2], w3 = wp[3];
    bf16x8 o0, o1;
    o0[0]=(__bf16)(s0[0]*w0[0]); o0[1]=(__bf16)(s0[1]*w0[1]);
    o0[2]=(__bf16)(s0[2]*w0[2]); o0[3]=(__bf16)(s0[3]*w0[3]);
    o0[4]=(__bf16)(s1[0]*w1[0]); o0[5]=(__bf16)(s1[1]*w1[1]);
    o0[6]=(__bf16)(s1[2]*w1[2]); o0[7]=(__bf16)(s1[3]*w1[3]);
    o1[0]=(__bf16)(s2[0]*w2[0]); o1[1]=(__bf16)(s2[1]*w2[1]);
    o1[2]=(__bf16)(s2[2]*w2[2]); o1[3]=(__bf16)(s2[3]*w2[3]);
    o1[4]=(__bf16)(s3[0]*w3[0]); o1[5]=(__bf16)(s3[1]*w3[1]);
    o1[6]=(__bf16)(s3[2]*w3[2]); o1[7]=(__bf16)(s3[3]*w3[3]);
    *(bf16x8*)(Abf + i)     = o0;
    *(bf16x8*)(Abf + i + 8) = o1;
}

// ---------------- coup partials = A(chunk) @ X : grid (128 m-blocks, KS=16) ----------------
// 2048 blocks x 4 waves, __launch_bounds__(256,8) pins VGPR<=64 -> 8 waves/SIMD.
// Depth-2 pipeline: 6 independent 16B loads in flight ahead of 4 MFMAs.
__global__ __launch_bounds__(256, 8) void gemm_step_k(const __bf16* __restrict__ Abf,
                                                      const __bf16* __restrict__ Xbf,
                                                      float* __restrict__ part) {
    int mb = blockIdx.x;
    int ks = blockIdx.y;
    int lane = threadIdx.x & 63;
    int w = threadIdx.x >> 6;
    int row = mb * 64 + w * 16 + (lane & 15);
    int kb  = (lane >> 4) * 8;
    int k0  = ks * (NN / KS);
    const int KC = NN / KS;  // 512
    f32x4 acc0 = {0.f,0.f,0.f,0.f}, acc1 = {0.f,0.f,0.f,0.f};
    const __bf16* bp0 = Xbf + (size_t)(lane & 15) * NN + k0 + kb;
    const __bf16* bp1 = bp0 + (size_t)16 * NN;
    const __bf16* ap = Abf + (size_t)row * NN + k0 + kb;
    bf16x8 a0  = *(const bf16x8*)(ap);
    bf16x8 a1  = *(const bf16x8*)(ap + 32);
    bf16x8 b00 = *(const bf16x8*)(bp0);
    bf16x8 b01 = *(const bf16x8*)(bp0 + 32);
    bf16x8 b10 = *(const bf16x8*)(bp1);
    bf16x8 b11 = *(const bf16x8*)(bp1 + 32);
    #pragma unroll
    for (int k = 0; k < KC - 64; k += 64) {
        bf16x8 na0  = *(const bf16x8*)(ap  + k + 64);
        bf16x8 na1  = *(const bf16x8*)(ap  + k + 96);
        bf16x8 nb00 = *(const bf16x8*)(bp0 + k + 64);
        bf16x8 nb01 = *(const bf16x8*)(bp0 + k + 96);
        bf16x8 nb10 = *(const bf16x8*)(bp1 + k + 64);
        bf16x8 nb11 = *(const bf16x8*)(bp1 + k + 96);
        acc0 = __builtin_amdgcn_mfma_f32_16x16x32_bf16(a0, b00, acc0, 0, 0, 0);
        acc1 = __builtin_amdgcn_mfma_f32_16x16x32_bf16(a0, b10, acc1, 0, 0, 0);
        acc0 = __builtin_amdgcn_mfma_f32_16x16x32_bf16(a1, b01, acc0, 0, 0, 0);
        acc1 = __builtin_amdgcn_mfma_f32_16x16x32_bf16(a1, b11, acc1, 0, 0, 0);
        a0 = na0; a1 = na1; b00 = nb00; b01 = nb01; b10 = nb10; b11 = nb11;
    }
    acc0 = __builtin_amdgcn_mfma_f32_16x16x32_bf16(a0, b00, acc0, 0, 0, 0);
    acc1 = __builtin_amdgcn_mfma_f32_16x16x32_bf16(a0, b10, acc1, 0, 0, 0);
    acc0 = __builtin_amdgcn_mfma_f32_16x16x32_bf16(a1, b01, acc0, 0, 0, 0);
    acc1 = __builtin_amdgcn_mfma_f32_16x16x32_bf16(a1, b11, acc1, 0, 0, 0);
    // C/D layout: col = lane&15, row = (lane>>4)*4 + r  [HW-verified]
    int orow = mb * 64 + w * 16 + (lane >> 4) * 4;
    int ocol = lane & 15;
    float* pp = part + (size_t)ks * NN * NBC + (size_t)orow * NBC + ocol;
    #pragma unroll
    for (int r = 0; r < 4; ++r) {
        pp[(size_t)r * NBC]      = acc0[r];
        pp[(size_t)r * NBC + 16] = acc1[r];
    }
}

// fallback: fused sc*cw conversion in the K-loop (used only if workspace too small)
__device__ inline bf16x8 mulcvt8(const float* __restrict__ s, const float* __restrict__ w) {
    f32x4 s0 = ((const f32x4*)s)[0], s1 = ((const f32x4*)s)[1];
    f32x4 w0 = ((const f32x4*)w)[0], w1 = ((const f32x4*)w)[1];
    bf16x8 r;
    r[0]=(__bf16)(s0[0]*w0[0]); r[1]=(__bf16)(s0[1]*w0[1]);
    r[2]=(__bf16)(s0[2]*w0[2]); r[3]=(__bf16)(s0[3]*w0[3]);
    r[4]=(__bf16)(s1[0]*w1[0]); r[5]=(__bf16)(s1[1]*w1[1]);
    r[6]=(__bf16)(s1[2]*w1[2]); r[7]=(__bf16)(s1[3]*w1[3]);
    return r;
}

__global__ __launch_bounds__(256) void gemm_step_fused_k(const float* __restrict__ sc,
                                                         const float* __restrict__ cw,
                                                         const __bf16* __restrict__ Xbf,
                                                         float* __restrict__ part) {
    int mb = blockIdx.x;
    int ks = blockIdx.y;
    int lane = threadIdx.x & 63;
    int w = threadIdx.x >> 6;
    int row = mb * 64 + w * 16 + (lane & 15);
    int kb  = (lane >> 4) * 8;
    int k0  = ks * (NN / KS);
    const int KC = NN / KS;
    f32x4 acc0 = {0.f,0.f,0.f,0.f}, acc1 = {0.f,0.f,0.f,0.f};
    const __bf16* bp0 = Xbf + (size_t)(lane & 15) * NN + k0 + kb;
    const __bf16* bp1 = bp0 + (size_t)16 * NN;
    const float* as = sc + (size_t)row * NN + k0 + kb;
    const float* aw = cw + (size_t)row * NN + k0 + kb;
    #pragma unroll 4
    for (int k = 0; k < KC; k += 32) {
        bf16x8 a  = mulcvt8(as + k, aw + k);
        bf16x8 b0 = *(const bf16x8*)(bp0 + k);
        bf16x8 b1 = *(const bf16x8*)(bp1 + k);
        acc0 = __builtin_amdgcn_mfma_f32_16x16x32_bf16(a, b0, acc0, 0, 0, 0);
        acc1 = __builtin_amdgcn_mfma_f32_16x16x32_bf16(a, b1, acc1, 0, 0, 0);
    }
    int orow = mb * 64 + w * 16 + (lane >> 4) * 4;
    int ocol = lane & 15;
    float* pp = part + (size_t)ks * NN * NBC + (size_t)orow * NBC + ocol;
    #pragma unroll
    for (int r = 0; r < 4; ++r) {
        pp[(size_t)r * NBC]      = acc0[r];
        pp[(size_t)r * NBC + 16] = acc1[r];
    }
}

// ---------------- oscillator update: channel bits in low lane bits for coalesced part read ----------------
__global__ void update_step_k(const float* __restrict__ part, const float* __restrict__ y_arr,
                              const float* __restrict__ omg, const float* __restrict__ gamma,
                              float* __restrict__ x0f, __bf16* __restrict__ Xbf,
                              float* __restrict__ out_k) {
    int tid = blockIdx.x * 256 + threadIdx.x;   // 131072
    int pi = tid & 15;          // (b, j)
    int b = pi >> 3, j = pi & 7;
    int n = tid >> 4;           // 0..8191
    int base = n * NBC + b * NC + 2 * j;
    float c0 = 0.f, c1 = 0.f;
    #pragma unroll
    for (int ks = 0; ks < KS; ++ks) {
        const float* p = part + (size_t)ks * NN * NBC + base;
        c0 += p[0]; c1 += p[1];
    }
    float y0 = y_arr[base] + c0;
    float y1 = y_arr[base + 1] + c1;
    size_t xi = ((size_t)(b * NN + n)) * NC + 2 * j;
    float x0 = x0f[xi], x1 = x0f[xi + 1];
    float sim = x0 * y0 + x1 * y1;
    float p0 = y0 - sim * x0;
    float p1 = y1 - sim * x1;
    float om = fabsf(omg[j]);
    float g  = gamma[0];
    float v0 = x0 + g * ( om * x1 + p0);
    float v1 = x1 + g * (-om * x0 + p1);
    float inv = 1.f / (sqrtf(v0*v0 + v1*v1) + 1e-6f);
    v0 *= inv; v1 *= inv;
    out_k[xi] = v0; out_k[xi + 1] = v1;
    x0f[xi] = v0; x0f[xi + 1] = v1;
    Xbf[(size_t)(b*NC + 2*j)     * NN + n] = (__bf16)v0;
    Xbf[(size_t)(b*NC + 2*j + 1) * NN + n] = (__bf16)v1;
}

extern "C" void kernel_launch(void* const* d_in, const int* in_sizes, int n_in,
                              void* d_out, int out_size, void* d_ws, size_t ws_size,
                              hipStream_t stream) {
    const float* x     = (const float*)d_in[0];
    const float* c     = (const float*)d_in[1];
    const float* sc    = (const float*)d_in[2];
    const float* gnw   = (const float*)d_in[3];
    const float* gnb   = (const float*)d_in[4];
    const float* cw    = (const float*)d_in[5];
    const float* omg   = (const float*)d_in[6];
    const float* gamma = (const float*)d_in[7];
    float* out = (float*)d_out;
    int Q = out_size / STEP_ELEMS;

    const size_t szA   = (size_t)NN * NN * 2;        // 128 MiB
    const size_t szXbf = (size_t)NBC * NN * 2;       // 512 KiB
    const size_t szX0f = (size_t)NB * NN * NC * 4;   // 1 MiB
    const size_t szY   = (size_t)NN * NBC * 4;       // 1 MiB
    const size_t szPart = (size_t)KS * NN * NBC * 4; // 16 MiB (f32)
    const size_t rest = szXbf + szX0f + szY + szPart + 256;
    bool bigws = ws_size >= szA + rest;

    char* p = (char*)d_ws;
    __bf16* Abf = nullptr;
    if (bigws) { Abf = (__bf16*)p; p += szA; }
    __bf16* Xbf  = (__bf16*)p; p += szXbf;
    float* x0f   = (float*)p;  p += szX0f;
    float* y_arr = (float*)p;  p += szY;
    float* part  = (float*)p;  p += szPart;
    float* stats = (float*)p;  p += 256;

    gn_stats_k<<<16, 256, 0, stream>>>(c, stats);
    prep_xy_k<<<(NB * NN * 8) / 256, 256, 0, stream>>>(x, c, gnw, gnb, stats, y_arr, x0f, Xbf);
    if (bigws) {
        const size_t chunk = (size_t)NN * NN / 8;    // 8 dispatches -> rocprof shows steps too
        for (int d = 0; d < 8; ++d)
            prep_A_k<<<chunk / 16 / 256, 256, 0, stream>>>(sc, cw, Abf, d * chunk);
    }

    dim3 gg(NN / 64, KS);
    for (int k = 0; k < Q; ++k) {
        if (bigws)
            gemm_step_k<<<gg, 256, 0, stream>>>(Abf, Xbf, part);
        else
            gemm_step_fused_k<<<gg, 256, 0, stream>>>(sc, cw, Xbf, part);
        update_step_k<<<(NB * NN * 8) / 256, 256, 0, stream>>>(
            part, y_arr, omg, gamma, x0f, Xbf, out + (size_t)k * STEP_ELEMS);
    }
}

// Round 7
// 506.695 us; speedup vs baseline: 1.9036x; 1.1134x over previous
//
#include <hip/hip_runtime.h>
#include <hip/hip_bf16.h>

#define NB 2
#define NC 16
#define NN 8192
#define NBC 32   // NB*NC columns of the skinny GEMM
#define KS 16    // fallback K-split factor
#define SROWS 16 // rows per block in fused step kernel
#define SWAVES 8 // waves per block in fused step kernel
#define STEP_ELEMS (NB * NN * NC)

typedef float f32x4 __attribute__((ext_vector_type(4)));
typedef __bf16 bf16x8 __attribute__((ext_vector_type(8)));

// ---------------- GroupNorm stats: one block per (b,g), 16 blocks ----------------
__global__ void gn_stats_k(const float* __restrict__ c, float* __restrict__ stats) {
    int bg = blockIdx.x;                       // b*8 + g
    const float* p = c + (size_t)bg * 16384;
    float s = 0.f, ss = 0.f;
    for (int i = threadIdx.x; i < 4096; i += 256) {
        float4 v = ((const float4*)p)[i];
        s  += v.x + v.y + v.z + v.w;
        ss += v.x*v.x + v.y*v.y + v.z*v.z + v.w*v.w;
    }
    #pragma unroll
    for (int o = 32; o; o >>= 1) { s += __shfl_down(s, o); ss += __shfl_down(ss, o); }
    __shared__ float sh[8];
    int w = threadIdx.x >> 6;
    if ((threadIdx.x & 63) == 0) { sh[w] = s; sh[w + 4] = ss; }
    __syncthreads();
    if (threadIdx.x == 0) {
        float S = sh[0]+sh[1]+sh[2]+sh[3], SS = sh[4]+sh[5]+sh[6]+sh[7];
        float mu = S * (1.f/16384.f);
        float var = SS * (1.f/16384.f) - mu*mu;
        stats[bg*2]   = mu;
        stats[bg*2+1] = rsqrtf(var + 1e-5f);
    }
}

// ---------------- y = GN(c)^T, x0 = normalize(x^T); write f32 state + bf16 X ----------------
__global__ void prep_xy_k(const float* __restrict__ x, const float* __restrict__ c,
                          const float* __restrict__ gnw, const float* __restrict__ gnb,
                          const float* __restrict__ stats,
                          float* __restrict__ y_arr, float* __restrict__ x0f,
                          __bf16* __restrict__ Xbf) {
    int tid = blockIdx.x * 256 + threadIdx.x;  // 131072 = B*N*8
    int n = tid & (NN - 1);
    int j = (tid >> 13) & 7;
    int b = tid >> 16;
    int ch0 = 2 * j;
    size_t r0 = ((size_t)(b * NC + ch0)) * NN + n;
    float c0 = c[r0], c1 = c[r0 + NN];
    float x0 = x[r0], x1 = x[r0 + NN];
    float mu = stats[(b*8 + j)*2], rstd = stats[(b*8 + j)*2 + 1];
    float y0 = (c0 - mu) * rstd * gnw[ch0]   + gnb[ch0];
    float y1 = (c1 - mu) * rstd * gnw[ch0+1] + gnb[ch0+1];
    int base = n * NBC + b * NC + ch0;
    y_arr[base] = y0; y_arr[base + 1] = y1;
    float inv = 1.f / (sqrtf(x0*x0 + x1*x1) + 1e-6f);
    x0 *= inv; x1 *= inv;
    size_t xi = ((size_t)(b * NN + n)) * NC + ch0;
    x0f[xi] = x0; x0f[xi + 1] = x1;
    Xbf[(size_t)(b*NC + ch0)     * NN + n] = (__bf16)x0;
    Xbf[(size_t)(b*NC + ch0 + 1) * NN + n] = (__bf16)x1;
}

// ---------------- A = bf16(sc * conn_w), 8 elems/thread (best measured variant) ----------------
__global__ void prep_A_k(const float* __restrict__ sc, const float* __restrict__ cw,
                         __bf16* __restrict__ Abf) {
    size_t i = ((size_t)blockIdx.x * 256 + threadIdx.x) * 8;
    f32x4 s0 = ((const f32x4*)(sc + i))[0], s1 = ((const f32x4*)(sc + i))[1];
    f32x4 w0 = ((const f32x4*)(cw + i))[0], w1 = ((const f32x4*)(cw + i))[1];
    bf16x8 o;
    o[0]=(__bf16)(s0[0]*w0[0]); o[1]=(__bf16)(s0[1]*w0[1]);
    o[2]=(__bf16)(s0[2]*w0[2]); o[3]=(__bf16)(s0[3]*w0[3]);
    o[4]=(__bf16)(s1[0]*w1[0]); o[5]=(__bf16)(s1[1]*w1[1]);
    o[6]=(__bf16)(s1[2]*w1[2]); o[7]=(__bf16)(s1[3]*w1[3]);
    *(bf16x8*)(Abf + i) = o;
}

// ---------------- fused step: coup = A @ X, LDS-reduce, oscillator update ----------------
// 512 blocks x 512 threads (2 blocks/CU, 4 waves/SIMD). Block mb owns rows
// [mb*16, +16); wave w covers k in [w*1024, +1024); depth-2 pipeline.
__global__ __launch_bounds__(512, 4) void step_k(
    const __bf16* __restrict__ Abf, const __bf16* __restrict__ Xc,
    __bf16* __restrict__ Xn, const float* __restrict__ y_arr,
    const float* __restrict__ omg, const float* __restrict__ gamma,
    float* __restrict__ x0f, float* __restrict__ out_k)
{
    __shared__ float red[SWAVES][SROWS][36];   // pad 36: 2-way (free) on write+read
    int tid = threadIdx.x;
    int lane = tid & 63, w = tid >> 6;
    int mb = blockIdx.x;
    const int KW = NN / SWAVES;                // 1024
    int k0 = w * KW;
    int row = mb * SROWS + (lane & 15);
    int kb  = (lane >> 4) * 8;

    const __bf16* ap  = Abf + (size_t)row * NN + k0 + kb;
    const __bf16* bp0 = Xc + (size_t)(lane & 15) * NN + k0 + kb;
    const __bf16* bp1 = bp0 + (size_t)16 * NN;

    f32x4 acc0 = {0.f,0.f,0.f,0.f}, acc1 = {0.f,0.f,0.f,0.f};
    bf16x8 a0  = *(const bf16x8*)(ap);
    bf16x8 a1  = *(const bf16x8*)(ap + 32);
    bf16x8 b00 = *(const bf16x8*)(bp0);
    bf16x8 b01 = *(const bf16x8*)(bp0 + 32);
    bf16x8 b10 = *(const bf16x8*)(bp1);
    bf16x8 b11 = *(const bf16x8*)(bp1 + 32);
    #pragma unroll
    for (int k = 0; k < KW - 64; k += 64) {
        bf16x8 na0  = *(const bf16x8*)(ap  + k + 64);
        bf16x8 na1  = *(const bf16x8*)(ap  + k + 96);
        bf16x8 nb00 = *(const bf16x8*)(bp0 + k + 64);
        bf16x8 nb01 = *(const bf16x8*)(bp0 + k + 96);
        bf16x8 nb10 = *(const bf16x8*)(bp1 + k + 64);
        bf16x8 nb11 = *(const bf16x8*)(bp1 + k + 96);
        acc0 = __builtin_amdgcn_mfma_f32_16x16x32_bf16(a0, b00, acc0, 0, 0, 0);
        acc1 = __builtin_amdgcn_mfma_f32_16x16x32_bf16(a0, b10, acc1, 0, 0, 0);
        acc0 = __builtin_amdgcn_mfma_f32_16x16x32_bf16(a1, b01, acc0, 0, 0, 0);
        acc1 = __builtin_amdgcn_mfma_f32_16x16x32_bf16(a1, b11, acc1, 0, 0, 0);
        a0 = na0; a1 = na1; b00 = nb00; b01 = nb01; b10 = nb10; b11 = nb11;
    }
    acc0 = __builtin_amdgcn_mfma_f32_16x16x32_bf16(a0, b00, acc0, 0, 0, 0);
    acc1 = __builtin_amdgcn_mfma_f32_16x16x32_bf16(a0, b10, acc1, 0, 0, 0);
    acc0 = __builtin_amdgcn_mfma_f32_16x16x32_bf16(a1, b01, acc0, 0, 0, 0);
    acc1 = __builtin_amdgcn_mfma_f32_16x16x32_bf16(a1, b11, acc1, 0, 0, 0);

    // C/D layout: col = lane&15, row = (lane>>4)*4 + r  [HW-verified]
    int orow = (lane >> 4) * 4, ocol = lane & 15;
    #pragma unroll
    for (int r4 = 0; r4 < 4; ++r4) {
        red[w][orow + r4][ocol]      = acc0[r4];
        red[w][orow + r4][ocol + 16] = acc1[r4];
    }
    __syncthreads();

    if (tid < SROWS * 16) {
        int pi = tid & 15, b = pi >> 3, j = pi & 7;
        int r_ = tid >> 4;
        int n_ = mb * SROWS + r_;
        int cb = b * NC + 2 * j;
        float c0 = 0.f, c1 = 0.f;
        #pragma unroll
        for (int ww = 0; ww < SWAVES; ++ww) {
            c0 += red[ww][r_][cb];
            c1 += red[ww][r_][cb + 1];
        }
        int yb = n_ * NBC + cb;
        float y0 = y_arr[yb] + c0;
        float y1 = y_arr[yb + 1] + c1;
        size_t xi = ((size_t)(b * NN + n_)) * NC + 2 * j;
        float x0 = x0f[xi], x1 = x0f[xi + 1];
        float sim = x0 * y0 + x1 * y1;
        float p0 = y0 - sim * x0;
        float p1 = y1 - sim * x1;
        float om = fabsf(omg[j]);
        float g  = gamma[0];
        float v0 = x0 + g * ( om * x1 + p0);
        float v1 = x1 + g * (-om * x0 + p1);
        float inv = 1.f / (sqrtf(v0*v0 + v1*v1) + 1e-6f);
        v0 *= inv; v1 *= inv;
        out_k[xi] = v0; out_k[xi + 1] = v1;
        x0f[xi] = v0; x0f[xi + 1] = v1;
        Xn[(size_t)cb * NN + n_]       = (__bf16)v0;
        Xn[(size_t)(cb + 1) * NN + n_] = (__bf16)v1;
    }
}

// ---------------- fallback path (workspace too small): fused sc*cw gemm + update ----------------
__device__ inline bf16x8 mulcvt8(const float* __restrict__ s, const float* __restrict__ w) {
    f32x4 s0 = ((const f32x4*)s)[0], s1 = ((const f32x4*)s)[1];
    f32x4 w0 = ((const f32x4*)w)[0], w1 = ((const f32x4*)w)[1];
    bf16x8 r;
    r[0]=(__bf16)(s0[0]*w0[0]); r[1]=(__bf16)(s0[1]*w0[1]);
    r[2]=(__bf16)(s0[2]*w0[2]); r[3]=(__bf16)(s0[3]*w0[3]);
    r[4]=(__bf16)(s1[0]*w1[0]); r[5]=(__bf16)(s1[1]*w1[1]);
    r[6]=(__bf16)(s1[2]*w1[2]); r[7]=(__bf16)(s1[3]*w1[3]);
    return r;
}

__global__ __launch_bounds__(256) void gemm_step_fused_k(const float* __restrict__ sc,
                                                         const float* __restrict__ cw,
                                                         const __bf16* __restrict__ Xbf,
                                                         float* __restrict__ part) {
    int mb = blockIdx.x;
    int ks = blockIdx.y;
    int lane = threadIdx.x & 63;
    int w = threadIdx.x >> 6;
    int row = mb * 64 + w * 16 + (lane & 15);
    int kb  = (lane >> 4) * 8;
    int k0  = ks * (NN / KS);
    const int KC = NN / KS;
    f32x4 acc0 = {0.f,0.f,0.f,0.f}, acc1 = {0.f,0.f,0.f,0.f};
    const __bf16* bp0 = Xbf + (size_t)(lane & 15) * NN + k0 + kb;
    const __bf16* bp1 = bp0 + (size_t)16 * NN;
    const float* as = sc + (size_t)row * NN + k0 + kb;
    const float* aw = cw + (size_t)row * NN + k0 + kb;
    #pragma unroll 4
    for (int k = 0; k < KC; k += 32) {
        bf16x8 a  = mulcvt8(as + k, aw + k);
        bf16x8 b0 = *(const bf16x8*)(bp0 + k);
        bf16x8 b1 = *(const bf16x8*)(bp1 + k);
        acc0 = __builtin_amdgcn_mfma_f32_16x16x32_bf16(a, b0, acc0, 0, 0, 0);
        acc1 = __builtin_amdgcn_mfma_f32_16x16x32_bf16(a, b1, acc1, 0, 0, 0);
    }
    int orow = mb * 64 + w * 16 + (lane >> 4) * 4;
    int ocol = lane & 15;
    float* pp = part + (size_t)ks * NN * NBC + (size_t)orow * NBC + ocol;
    #pragma unroll
    for (int r = 0; r < 4; ++r) {
        pp[(size_t)r * NBC]      = acc0[r];
        pp[(size_t)r * NBC + 16] = acc1[r];
    }
}

__global__ void update_step_k(const float* __restrict__ part, const float* __restrict__ y_arr,
                              const float* __restrict__ omg, const float* __restrict__ gamma,
                              float* __restrict__ x0f, __bf16* __restrict__ Xbf,
                              float* __restrict__ out_k) {
    int tid = blockIdx.x * 256 + threadIdx.x;   // 131072
    int pi = tid & 15;
    int b = pi >> 3, j = pi & 7;
    int n = tid >> 4;
    int base = n * NBC + b * NC + 2 * j;
    float c0 = 0.f, c1 = 0.f;
    #pragma unroll
    for (int ks = 0; ks < KS; ++ks) {
        const float* p = part + (size_t)ks * NN * NBC + base;
        c0 += p[0]; c1 += p[1];
    }
    float y0 = y_arr[base] + c0;
    float y1 = y_arr[base + 1] + c1;
    size_t xi = ((size_t)(b * NN + n)) * NC + 2 * j;
    float x0 = x0f[xi], x1 = x0f[xi + 1];
    float sim = x0 * y0 + x1 * y1;
    float p0 = y0 - sim * x0;
    float p1 = y1 - sim * x1;
    float om = fabsf(omg[j]);
    float g  = gamma[0];
    float v0 = x0 + g * ( om * x1 + p0);
    float v1 = x1 + g * (-om * x0 + p1);
    float inv = 1.f / (sqrtf(v0*v0 + v1*v1) + 1e-6f);
    v0 *= inv; v1 *= inv;
    out_k[xi] = v0; out_k[xi + 1] = v1;
    x0f[xi] = v0; x0f[xi + 1] = v1;
    Xbf[(size_t)(b*NC + 2*j)     * NN + n] = (__bf16)v0;
    Xbf[(size_t)(b*NC + 2*j + 1) * NN + n] = (__bf16)v1;
}

extern "C" void kernel_launch(void* const* d_in, const int* in_sizes, int n_in,
                              void* d_out, int out_size, void* d_ws, size_t ws_size,
                              hipStream_t stream) {
    const float* x     = (const float*)d_in[0];
    const float* c     = (const float*)d_in[1];
    const float* sc    = (const float*)d_in[2];
    const float* gnw   = (const float*)d_in[3];
    const float* gnb   = (const float*)d_in[4];
    const float* cw    = (const float*)d_in[5];
    const float* omg   = (const float*)d_in[6];
    const float* gamma = (const float*)d_in[7];
    float* out = (float*)d_out;
    int Q = out_size / STEP_ELEMS;

    const size_t szA   = (size_t)NN * NN * 2;        // 128 MiB
    const size_t szX   = (size_t)NBC * NN * 2;       // 512 KiB each (double-buffered)
    const size_t szX0f = (size_t)NB * NN * NC * 4;   // 1 MiB
    const size_t szY   = (size_t)NN * NBC * 4;       // 1 MiB
    const size_t szPart = (size_t)KS * NN * NBC * 4; // 16 MiB (fallback only)
    const size_t rest = 2*szX + szX0f + szY + szPart + 256;
    bool bigws = ws_size >= szA + rest;

    char* p = (char*)d_ws;
    __bf16* Abf = nullptr;
    if (bigws) { Abf = (__bf16*)p; p += szA; }
    __bf16* Xa   = (__bf16*)p; p += szX;
    __bf16* Xb   = (__bf16*)p; p += szX;
    float* x0f   = (float*)p;  p += szX0f;
    float* y_arr = (float*)p;  p += szY;
    float* part  = (float*)p;  p += szPart;
    float* stats = (float*)p;  p += 256;

    gn_stats_k<<<16, 256, 0, stream>>>(c, stats);
    prep_xy_k<<<(NB * NN * 8) / 256, 256, 0, stream>>>(x, c, gnw, gnb, stats, y_arr, x0f, Xa);

    if (bigws) {
        prep_A_k<<<((size_t)NN * NN / 8) / 256, 256, 0, stream>>>(sc, cw, Abf);
        __bf16* Xc = Xa; __bf16* Xn = Xb;
        for (int q = 0; q < Q; ++q) {
            step_k<<<NN / SROWS, SWAVES * 64, 0, stream>>>(
                Abf, Xc, Xn, y_arr, omg, gamma, x0f, out + (size_t)q * STEP_ELEMS);
            __bf16* t = Xc; Xc = Xn; Xn = t;
        }
    } else {
        dim3 gg(NN / 64, KS);
        for (int q = 0; q < Q; ++q) {
            gemm_step_fused_k<<<gg, 256, 0, stream>>>(sc, cw, Xa, part);
            update_step_k<<<(NB * NN * 8) / 256, 256, 0, stream>>>(
                part, y_arr, omg, gamma, x0f, Xa, out + (size_t)q * STEP_ELEMS);
        }
    }
}

// Round 10
// 491.215 us; speedup vs baseline: 1.9636x; 1.0315x over previous
//
#include <hip/hip_runtime.h>
#include <hip/hip_bf16.h>

#define NB 2
#define NC 16
#define NN 8192
#define NBC 32    // NB*NC columns of the skinny GEMM
#define KS 16     // fallback K-split factor
#define SROWS 16  // rows per block in staged gemm
#define SWAVES 8  // waves per block in staged gemm
#define KCH 512   // k-chunk staged per LDS buffer
#define NCHUNK (NN / KCH)   // 16
#define ROWPITCH 520        // bf16 elems per LDS row (512 + 8 pad)
#define STEP_ELEMS (NB * NN * NC)

typedef float f32x4 __attribute__((ext_vector_type(4)));
typedef __bf16 bf16x8 __attribute__((ext_vector_type(8)));

// ---------------- GroupNorm stats: one block per (b,g), 16 blocks ----------------
__global__ void gn_stats_k(const float* __restrict__ c, float* __restrict__ stats) {
    int bg = blockIdx.x;                       // b*8 + g
    const float* p = c + (size_t)bg * 16384;
    float s = 0.f, ss = 0.f;
    for (int i = threadIdx.x; i < 4096; i += 256) {
        float4 v = ((const float4*)p)[i];
        s  += v.x + v.y + v.z + v.w;
        ss += v.x*v.x + v.y*v.y + v.z*v.z + v.w*v.w;
    }
    #pragma unroll
    for (int o = 32; o; o >>= 1) { s += __shfl_down(s, o); ss += __shfl_down(ss, o); }
    __shared__ float sh[8];
    int w = threadIdx.x >> 6;
    if ((threadIdx.x & 63) == 0) { sh[w] = s; sh[w + 4] = ss; }
    __syncthreads();
    if (threadIdx.x == 0) {
        float S = sh[0]+sh[1]+sh[2]+sh[3], SS = sh[4]+sh[5]+sh[6]+sh[7];
        float mu = S * (1.f/16384.f);
        float var = SS * (1.f/16384.f) - mu*mu;
        stats[bg*2]   = mu;
        stats[bg*2+1] = rsqrtf(var + 1e-5f);
    }
}

// ---------------- y = GN(c)^T, x0 = normalize(x^T); write f32 state + bf16 X ----------------
__global__ void prep_xy_k(const float* __restrict__ x, const float* __restrict__ c,
                          const float* __restrict__ gnw, const float* __restrict__ gnb,
                          const float* __restrict__ stats,
                          float* __restrict__ y_arr, float* __restrict__ x0f,
                          __bf16* __restrict__ Xbf) {
    int tid = blockIdx.x * 256 + threadIdx.x;  // 131072 = B*N*8
    int n = tid & (NN - 1);
    int j = (tid >> 13) & 7;
    int b = tid >> 16;
    int ch0 = 2 * j;
    size_t r0 = ((size_t)(b * NC + ch0)) * NN + n;
    float c0 = c[r0], c1 = c[r0 + NN];
    float x0 = x[r0], x1 = x[r0 + NN];
    float mu = stats[(b*8 + j)*2], rstd = stats[(b*8 + j)*2 + 1];
    float y0 = (c0 - mu) * rstd * gnw[ch0]   + gnb[ch0];
    float y1 = (c1 - mu) * rstd * gnw[ch0+1] + gnb[ch0+1];
    int base = n * NBC + b * NC + ch0;
    y_arr[base] = y0; y_arr[base + 1] = y1;
    float inv = 1.f / (sqrtf(x0*x0 + x1*x1) + 1e-6f);
    x0 *= inv; x1 *= inv;
    size_t xi = ((size_t)(b * NN + n)) * NC + ch0;
    x0f[xi] = x0; x0f[xi + 1] = x1;
    Xbf[(size_t)(b*NC + ch0)     * NN + n] = (__bf16)x0;
    Xbf[(size_t)(b*NC + ch0 + 1) * NN + n] = (__bf16)x1;
}

// ---------------- A = bf16(sc * conn_w), 8 elems/thread (best measured variant) ----------------
__global__ void prep_A_k(const float* __restrict__ sc, const float* __restrict__ cw,
                         __bf16* __restrict__ Abf) {
    size_t i = ((size_t)blockIdx.x * 256 + threadIdx.x) * 8;
    f32x4 s0 = ((const f32x4*)(sc + i))[0], s1 = ((const f32x4*)(sc + i))[1];
    f32x4 w0 = ((const f32x4*)(cw + i))[0], w1 = ((const f32x4*)(cw + i))[1];
    bf16x8 o;
    o[0]=(__bf16)(s0[0]*w0[0]); o[1]=(__bf16)(s0[1]*w0[1]);
    o[2]=(__bf16)(s0[2]*w0[2]); o[3]=(__bf16)(s0[3]*w0[3]);
    o[4]=(__bf16)(s1[0]*w1[0]); o[5]=(__bf16)(s1[1]*w1[1]);
    o[6]=(__bf16)(s1[2]*w1[2]); o[7]=(__bf16)(s1[3]*w1[3]);
    *(bf16x8*)(Abf + i) = o;
}

// ---------------- staged GEMM: coup = A @ X (full K per block), writes coup[NN][NBC] ----------------
// 512 blocks x 512 threads. Per chunk: each wave stages 2 rows of the next
// chunk (1 KiB contiguous global_load_lds each), MFMAs the current buffer.
__global__ __launch_bounds__(512, 4) void gemm_stage_k(
    const __bf16* __restrict__ Abf, const __bf16* __restrict__ Xc,
    float* __restrict__ coup)
{
    __shared__ __align__(16) __bf16 Abuf[2][SROWS * ROWPITCH];  // 2 x 16.25 KiB
    __shared__ float red[SWAVES][SROWS][36];
    int tid = threadIdx.x;
    int lane = tid & 63, w = tid >> 6;
    int mb = blockIdx.x;

    // staging: wave w owns rows 2w, 2w+1 of the block's 16-row panel
    int r0 = 2 * w;
    const __bf16* asrc0 = Abf + (size_t)(mb * SROWS + r0) * NN + lane * 8;
    const __bf16* asrc1 = asrc0 + NN;

    // fragment geometry: wave w covers k-window [w*64, w*64+64) of each chunk
    int fr = lane & 15;            // row (A) / col (X)
    int kg = (lane >> 4) * 8;      // k sub-offset within 32
    const __bf16* xb0 = Xc + (size_t)fr * NN + w * 64 + kg;      // cols 0-15
    const __bf16* xb1 = xb0 + (size_t)16 * NN;                   // cols 16-31
    const __bf16* ab  = &Abuf[0][fr * ROWPITCH + w * 64 + kg];
    const int abstride = SROWS * ROWPITCH;

    f32x4 acc0 = {0.f,0.f,0.f,0.f}, acc1 = {0.f,0.f,0.f,0.f};

    // prologue: stage chunk 0 into buf 0
    __builtin_amdgcn_global_load_lds(
        (const __attribute__((address_space(1))) void*)(asrc0),
        (__attribute__((address_space(3))) void*)(&Abuf[0][r0 * ROWPITCH]), 16, 0, 0);
    __builtin_amdgcn_global_load_lds(
        (const __attribute__((address_space(1))) void*)(asrc1),
        (__attribute__((address_space(3))) void*)(&Abuf[0][(r0 + 1) * ROWPITCH]), 16, 0, 0);
    __syncthreads();

    int buf = 0;
    for (int c = 0; c < NCHUNK; ++c) {
        // X fragments first (their vmcnt wait leaves staging outstanding)
        bf16x8 b00 = *(const bf16x8*)(xb0 + c * KCH);
        bf16x8 b01 = *(const bf16x8*)(xb0 + c * KCH + 32);
        bf16x8 b10 = *(const bf16x8*)(xb1 + c * KCH);
        bf16x8 b11 = *(const bf16x8*)(xb1 + c * KCH + 32);
        if (c + 1 < NCHUNK) {
            int nb = buf ^ 1;
            __builtin_amdgcn_global_load_lds(
                (const __attribute__((address_space(1))) void*)(asrc0 + (c + 1) * KCH),
                (__attribute__((address_space(3))) void*)(&Abuf[nb][r0 * ROWPITCH]), 16, 0, 0);
            __builtin_amdgcn_global_load_lds(
                (const __attribute__((address_space(1))) void*)(asrc1 + (c + 1) * KCH),
                (__attribute__((address_space(3))) void*)(&Abuf[nb][(r0 + 1) * ROWPITCH]), 16, 0, 0);
        }
        const __bf16* ac = ab + buf * abstride;
        bf16x8 a0 = *(const bf16x8*)(ac);
        bf16x8 a1 = *(const bf16x8*)(ac + 32);
        acc0 = __builtin_amdgcn_mfma_f32_16x16x32_bf16(a0, b00, acc0, 0, 0, 0);
        acc1 = __builtin_amdgcn_mfma_f32_16x16x32_bf16(a0, b10, acc1, 0, 0, 0);
        acc0 = __builtin_amdgcn_mfma_f32_16x16x32_bf16(a1, b01, acc0, 0, 0, 0);
        acc1 = __builtin_amdgcn_mfma_f32_16x16x32_bf16(a1, b11, acc1, 0, 0, 0);
        __syncthreads();   // drains staging (next buf ready) + protects buf reuse
        buf ^= 1;
    }

    // C/D layout: col = lane&15, row = (lane>>4)*4 + r  [HW-verified]
    int orow = (lane >> 4) * 4, ocol = lane & 15;
    #pragma unroll
    for (int r4 = 0; r4 < 4; ++r4) {
        red[w][orow + r4][ocol]      = acc0[r4];
        red[w][orow + r4][ocol + 16] = acc1[r4];
    }
    __syncthreads();

    if (tid < SROWS * 16) {
        int ch2 = tid & 15;            // pair of channels (0..15) -> cols 2*ch2, 2*ch2+1
        int r_  = tid >> 4;
        float c0 = 0.f, c1 = 0.f;
        #pragma unroll
        for (int ww = 0; ww < SWAVES; ++ww) {
            c0 += red[ww][r_][2 * ch2];
            c1 += red[ww][r_][2 * ch2 + 1];
        }
        int n_ = mb * SROWS + r_;
        coup[(size_t)n_ * NBC + 2 * ch2]     = c0;
        coup[(size_t)n_ * NBC + 2 * ch2 + 1] = c1;
    }
}

// ---------------- oscillator update: reads coup, updates Xbf IN PLACE (proven-safe handoff) ----------------
__global__ void update_coup_k(const float* __restrict__ coup, const float* __restrict__ y_arr,
                              const float* __restrict__ omg, const float* __restrict__ gamma,
                              float* __restrict__ x0f, __bf16* __restrict__ Xbf,
                              float* __restrict__ out_k) {
    int tid = blockIdx.x * 256 + threadIdx.x;   // 131072
    int pi = tid & 15;
    int b = pi >> 3, j = pi & 7;
    int n = tid >> 4;
    int base = n * NBC + b * NC + 2 * j;
    float c0 = coup[base];
    float c1 = coup[base + 1];
    float y0 = y_arr[base] + c0;
    float y1 = y_arr[base + 1] + c1;
    size_t xi = ((size_t)(b * NN + n)) * NC + 2 * j;
    float x0 = x0f[xi], x1 = x0f[xi + 1];
    float sim = x0 * y0 + x1 * y1;
    float p0 = y0 - sim * x0;
    float p1 = y1 - sim * x1;
    float om = fabsf(omg[j]);
    float g  = gamma[0];
    float v0 = x0 + g * ( om * x1 + p0);
    float v1 = x1 + g * (-om * x0 + p1);
    float inv = 1.f / (sqrtf(v0*v0 + v1*v1) + 1e-6f);
    v0 *= inv; v1 *= inv;
    out_k[xi] = v0; out_k[xi + 1] = v1;
    x0f[xi] = v0; x0f[xi + 1] = v1;
    Xbf[(size_t)(b*NC + 2*j)     * NN + n] = (__bf16)v0;
    Xbf[(size_t)(b*NC + 2*j + 1) * NN + n] = (__bf16)v1;
}

// ---------------- fallback path (workspace too small): fused sc*cw gemm + KS update ----------------
__device__ inline bf16x8 mulcvt8(const float* __restrict__ s, const float* __restrict__ w) {
    f32x4 s0 = ((const f32x4*)s)[0], s1 = ((const f32x4*)s)[1];
    f32x4 w0 = ((const f32x4*)w)[0], w1 = ((const f32x4*)w)[1];
    bf16x8 r;
    r[0]=(__bf16)(s0[0]*w0[0]); r[1]=(__bf16)(s0[1]*w0[1]);
    r[2]=(__bf16)(s0[2]*w0[2]); r[3]=(__bf16)(s0[3]*w0[3]);
    r[4]=(__bf16)(s1[0]*w1[0]); r[5]=(__bf16)(s1[1]*w1[1]);
    r[6]=(__bf16)(s1[2]*w1[2]); r[7]=(__bf16)(s1[3]*w1[3]);
    return r;
}

__global__ __launch_bounds__(256) void gemm_step_fused_k(const float* __restrict__ sc,
                                                         const float* __restrict__ cw,
                                                         const __bf16* __restrict__ Xbf,
                                                         float* __restrict__ part) {
    int mb = blockIdx.x;
    int ks = blockIdx.y;
    int lane = threadIdx.x & 63;
    int w = threadIdx.x >> 6;
    int row = mb * 64 + w * 16 + (lane & 15);
    int kb  = (lane >> 4) * 8;
    int k0  = ks * (NN / KS);
    const int KC = NN / KS;
    f32x4 acc0 = {0.f,0.f,0.f,0.f}, acc1 = {0.f,0.f,0.f,0.f};
    const __bf16* bp0 = Xbf + (size_t)(lane & 15) * NN + k0 + kb;
    const __bf16* bp1 = bp0 + (size_t)16 * NN;
    const float* as = sc + (size_t)row * NN + k0 + kb;
    const float* aw = cw + (size_t)row * NN + k0 + kb;
    #pragma unroll 4
    for (int k = 0; k < KC; k += 32) {
        bf16x8 a  = mulcvt8(as + k, aw + k);
        bf16x8 b0 = *(const bf16x8*)(bp0 + k);
        bf16x8 b1 = *(const bf16x8*)(bp1 + k);
        acc0 = __builtin_amdgcn_mfma_f32_16x16x32_bf16(a, b0, acc0, 0, 0, 0);
        acc1 = __builtin_amdgcn_mfma_f32_16x16x32_bf16(a, b1, acc1, 0, 0, 0);
    }
    int orow = mb * 64 + w * 16 + (lane >> 4) * 4;
    int ocol = lane & 15;
    float* pp = part + (size_t)ks * NN * NBC + (size_t)orow * NBC + ocol;
    #pragma unroll
    for (int r = 0; r < 4; ++r) {
        pp[(size_t)r * NBC]      = acc0[r];
        pp[(size_t)r * NBC + 16] = acc1[r];
    }
}

__global__ void update_step_k(const float* __restrict__ part, const float* __restrict__ y_arr,
                              const float* __restrict__ omg, const float* __restrict__ gamma,
                              float* __restrict__ x0f, __bf16* __restrict__ Xbf,
                              float* __restrict__ out_k) {
    int tid = blockIdx.x * 256 + threadIdx.x;   // 131072
    int pi = tid & 15;
    int b = pi >> 3, j = pi & 7;
    int n = tid >> 4;
    int base = n * NBC + b * NC + 2 * j;
    float c0 = 0.f, c1 = 0.f;
    #pragma unroll
    for (int ks = 0; ks < KS; ++ks) {
        const float* p = part + (size_t)ks * NN * NBC + base;
        c0 += p[0]; c1 += p[1];
    }
    float y0 = y_arr[base] + c0;
    float y1 = y_arr[base + 1] + c1;
    size_t xi = ((size_t)(b * NN + n)) * NC + 2 * j;
    float x0 = x0f[xi], x1 = x0f[xi + 1];
    float sim = x0 * y0 + x1 * y1;
    float p0 = y0 - sim * x0;
    float p1 = y1 - sim * x1;
    float om = fabsf(omg[j]);
    float g  = gamma[0];
    float v0 = x0 + g * ( om * x1 + p0);
    float v1 = x1 + g * (-om * x0 + p1);
    float inv = 1.f / (sqrtf(v0*v0 + v1*v1) + 1e-6f);
    v0 *= inv; v1 *= inv;
    out_k[xi] = v0; out_k[xi + 1] = v1;
    x0f[xi] = v0; x0f[xi + 1] = v1;
    Xbf[(size_t)(b*NC + 2*j)     * NN + n] = (__bf16)v0;
    Xbf[(size_t)(b*NC + 2*j + 1) * NN + n] = (__bf16)v1;
}

extern "C" void kernel_launch(void* const* d_in, const int* in_sizes, int n_in,
                              void* d_out, int out_size, void* d_ws, size_t ws_size,
                              hipStream_t stream) {
    const float* x     = (const float*)d_in[0];
    const float* c     = (const float*)d_in[1];
    const float* sc    = (const float*)d_in[2];
    const float* gnw   = (const float*)d_in[3];
    const float* gnb   = (const float*)d_in[4];
    const float* cw    = (const float*)d_in[5];
    const float* omg   = (const float*)d_in[6];
    const float* gamma = (const float*)d_in[7];
    float* out = (float*)d_out;
    int Q = out_size / STEP_ELEMS;

    const size_t szA    = (size_t)NN * NN * 2;        // 128 MiB
    const size_t szX    = (size_t)NBC * NN * 2;       // 512 KiB
    const size_t szX0f  = (size_t)NB * NN * NC * 4;   // 1 MiB
    const size_t szY    = (size_t)NN * NBC * 4;       // 1 MiB
    const size_t szCoup = (size_t)NN * NBC * 4;       // 1 MiB
    const size_t szPart = (size_t)KS * NN * NBC * 4;  // 16 MiB (fallback only)
    const size_t rest = szX + szX0f + szY + szCoup + szPart + 256;
    bool bigws = ws_size >= szA + rest;

    char* p = (char*)d_ws;
    __bf16* Abf = nullptr;
    if (bigws) { Abf = (__bf16*)p; p += szA; }
    __bf16* Xbf  = (__bf16*)p; p += szX;
    float* x0f   = (float*)p;  p += szX0f;
    float* y_arr = (float*)p;  p += szY;
    float* coup  = (float*)p;  p += szCoup;
    float* part  = (float*)p;  p += szPart;
    float* stats = (float*)p;  p += 256;

    gn_stats_k<<<16, 256, 0, stream>>>(c, stats);
    prep_xy_k<<<(NB * NN * 8) / 256, 256, 0, stream>>>(x, c, gnw, gnb, stats, y_arr, x0f, Xbf);

    if (bigws) {
        prep_A_k<<<((size_t)NN * NN / 8) / 256, 256, 0, stream>>>(sc, cw, Abf);
        for (int q = 0; q < Q; ++q) {
            gemm_stage_k<<<NN / SROWS, SWAVES * 64, 0, stream>>>(Abf, Xbf, coup);
            update_coup_k<<<(NB * NN * 8) / 256, 256, 0, stream>>>(
                coup, y_arr, omg, gamma, x0f, Xbf, out + (size_t)q * STEP_ELEMS);
        }
    } else {
        dim3 gg(NN / 64, KS);
        for (int q = 0; q < Q; ++q) {
            gemm_step_fused_k<<<gg, 256, 0, stream>>>(sc, cw, Xbf, part);
            update_step_k<<<(NB * NN * 8) / 256, 256, 0, stream>>>(
                part, y_arr, omg, gamma, x0f, Xbf, out + (size_t)q * STEP_ELEMS);
        }
    }
}